// Round 6
// baseline (232.769 us; speedup 1.0000x reference)
//
#include <hip/hip_runtime.h>
#include <stdint.h>

#define B_  2
#define S_  768
#define D_  768
#define H_  8
#define DH_ 96

typedef unsigned short ushort_t;
typedef __bf16 bf16x8 __attribute__((ext_vector_type(8)));
typedef float  f32x4  __attribute__((ext_vector_type(4)));

__device__ inline ushort_t f2bf(float f) {
    union { float f; unsigned int u; } v; v.f = f;
    unsigned int u = v.u;
    unsigned int r = u + 0x7fffu + ((u >> 16) & 1u);
    return (ushort_t)(r >> 16);
}
__device__ inline float bf2f(ushort_t u) {
    union { unsigned int i; float f; } c; c.i = ((unsigned int)u) << 16;
    return c.f;
}

// async global->LDS, 16B per lane; LDS dest is wave-uniform base + lane*16
__device__ inline void glds16(const void* gp, void* lp) {
    auto g = reinterpret_cast<const __attribute__((address_space(1))) uint32_t*>(
        reinterpret_cast<uintptr_t>(gp));
    auto l = reinterpret_cast<__attribute__((address_space(3))) uint32_t*>(
        reinterpret_cast<uintptr_t>(lp));
    __builtin_amdgcn_global_load_lds(g, l, 16, 0, 0);
}

// ---------------------------------------------------------------- convert
__global__ __launch_bounds__(256) void k_convert(
        const float* __restrict__ X, const float* __restrict__ Wq,
        const float* __restrict__ Wk, const float* __restrict__ Wv,
        const float* __restrict__ Wo,
        ushort_t* __restrict__ Xb, ushort_t* __restrict__ Wb) {
    const int NX4 = (B_ * S_ * D_) / 4;   // 294912
    const int NW4 = (D_ * D_) / 4;        // 147456
    int i = blockIdx.x * blockDim.x + threadIdx.x;
    float4 v;
    ushort_t* dst;
    if (i < NX4) {
        v = ((const float4*)X)[i];
        dst = Xb + i * 4;
    } else {
        int wi = i - NX4;
        int sel = wi / NW4;
        int off = wi - sel * NW4;
        const float* src = (sel == 0) ? Wq : (sel == 1) ? Wk : (sel == 2) ? Wv : Wo;
        v = ((const float4*)src)[off];
        dst = Wb + wi * 4;
    }
    ushort4 o;
    o.x = f2bf(v.x); o.y = f2bf(v.y); o.z = f2bf(v.z); o.w = f2bf(v.w);
    *(ushort4*)dst = o;
}

// ---------------------------------------------------------------- QKV GEMM 128x128 (m97-style)
// grid (18, 12). 4 waves, each owns a 64x64 quadrant (4x4 mfma accs).
__global__ __launch_bounds__(256) void k_qkv(
        const ushort_t* __restrict__ Xb, const ushort_t* __restrict__ Wb,
        const float* __restrict__ bq, const float* __restrict__ bk,
        const float* __restrict__ bv,
        ushort_t* __restrict__ Qb, ushort_t* __restrict__ Kb,
        ushort_t* __restrict__ Vtb) {
    __shared__ __align__(16) ushort_t As[128 * 32];
    __shared__ __align__(16) ushort_t Bs[128 * 32];
    const int tid = threadIdx.x, lane = tid & 63, w = tid >> 6;
    const int frn = lane & 15, fko = (lane >> 4) * 8, frg4 = (lane >> 4) * 4;
    const int wm = (w & 1) * 64, wn = (w >> 1) * 64;
    const int m0 = blockIdx.y * 128, n0 = blockIdx.x * 128;
    const int sr = w * 32 + (lane >> 2), sc = (lane & 3) * 8;
    const ushort_t* Ap = Xb + (size_t)(m0 + sr) * D_ + sc;
    const ushort_t* Bp = Wb + (size_t)(n0 + sr) * D_ + sc;
    ushort_t* AsW = As + w * 1024;
    ushort_t* BsW = Bs + w * 1024;
    f32x4 acc[4][4];
    #pragma unroll
    for (int i = 0; i < 4; i++)
        #pragma unroll
        for (int j = 0; j < 4; j++) acc[i][j] = (f32x4){0.f, 0.f, 0.f, 0.f};
    for (int kt = 0; kt < D_; kt += 32) {
        if (kt) __syncthreads();
        glds16(Ap + kt, AsW);
        glds16(Ap + 16 * D_ + kt, AsW + 512);
        glds16(Bp + kt, BsW);
        glds16(Bp + 16 * D_ + kt, BsW + 512);
        __syncthreads();
        bf16x8 a[4], b[4];
        #pragma unroll
        for (int mi = 0; mi < 4; mi++)
            a[mi] = *(const bf16x8*)&As[(wm + mi * 16 + frn) * 32 + fko];
        #pragma unroll
        for (int ni = 0; ni < 4; ni++)
            b[ni] = *(const bf16x8*)&Bs[(wn + ni * 16 + frn) * 32 + fko];
        #pragma unroll
        for (int mi = 0; mi < 4; mi++)
            #pragma unroll
            for (int ni = 0; ni < 4; ni++)
                acc[mi][ni] = __builtin_amdgcn_mfma_f32_16x16x32_bf16(a[mi], b[ni], acc[mi][ni], 0, 0, 0);
    }
    const int g = n0 / D_;                  // block-uniform (128 | 768)
    const float* bias_p = (g == 0) ? bq : (g == 1) ? bk : bv;
    #pragma unroll
    for (int ni = 0; ni < 4; ni++) {
        int gcol = n0 + wn + ni * 16 + frn;
        int d768 = gcol - g * D_;
        int h = d768 / DH_, d = d768 - h * DH_;
        float bias = bias_p[d768];
        #pragma unroll
        for (int mi = 0; mi < 4; mi++) {
            #pragma unroll
            for (int r = 0; r < 4; r++) {
                int grow = m0 + wm + mi * 16 + frg4 + r;
                int bidx = grow / S_, s = grow - bidx * S_;
                ushort_t ob = f2bf(acc[mi][ni][r] + bias);
                int bh = bidx * H_ + h;
                if (g == 0)      Qb[((size_t)bh * S_ + s) * DH_ + d] = ob;
                else if (g == 1) Kb[((size_t)bh * S_ + s) * DH_ + d] = ob;
                else             Vtb[((size_t)bh * DH_ + d) * S_ + s] = ob;
            }
        }
    }
}

// ---------------------------------------------------------------- fused flash v4
// XCD-pinned grid 384 (h*48 + b*24 + r0t). 32 q-rows/block. qcoef fused in
// prologue. Loop1: 24 chunks x 32 cols, LDS dbuf (1 barrier/chunk), FULLY
// UNROLLED so acc[24] stays in VGPRs (R3-R5 had it spilled to scratch:
// VGPR_Count 68 < 96 needed). Loop2: 24 steps, V+Ps LDS dbuf, unrolled.
#define KSLD 104   // K-tile row stride (bf16): 208B = 20 banks mod 32 -> 2-way max
#define DLD  36    // dist/ang row stride (f32)
#define L1B  15872 // Ks 6656 + Dd 4608 + Da 4608
__global__ __launch_bounds__(256) void k_flash(
        const ushort_t* __restrict__ Qb, const ushort_t* __restrict__ Kb,
        const ushort_t* __restrict__ Vtb,
        const float* __restrict__ Wd, const float* __restrict__ bd,
        const float* __restrict__ Wa, const float* __restrict__ ba,
        const float* __restrict__ distm, const float* __restrict__ angm,
        const float* __restrict__ mask,
        float* __restrict__ probs, ushort_t* __restrict__ Ctxb) {
    __shared__ __align__(16) char sm[35840];
    float* mstat = (float*)(sm + 31744);   // [2][32]
    float* lstat = (float*)(sm + 32000);   // [2][32]
    float* linv  = (float*)(sm + 32256);   // [32]
    float* Ms    = (float*)(sm + 32384);   // [768]
    float* qcS   = (float*)(sm + 35456);   // [32][3]
    const int idx = blockIdx.x;
    const int h = idx / 48, rem = idx - h * 48;
    const int b = rem / 24, r0 = (rem - b * 24) * 32;
    const int bh = b * H_ + h;
    const int tid = threadIdx.x, lane = tid & 63, w = tid >> 6;
    const int frn = lane & 15, fko = (lane >> 4) * 8, frg4 = (lane >> 4) * 4;
    const int rg = w & 1, cp = w >> 1;
    const ushort_t* Qbh = Qb + (size_t)bh * S_ * DH_;
    const ushort_t* Kbh = Kb + (size_t)bh * S_ * DH_;
    const ushort_t* Vbh = Vtb + (size_t)bh * DH_ * S_;

    // mask pre-stage
    Ms[tid]       = (1.0f - mask[b * S_ + tid])       * -10000.0f;
    Ms[tid + 256] = (1.0f - mask[b * S_ + tid + 256]) * -10000.0f;
    Ms[tid + 512] = (1.0f - mask[b * S_ + tid + 512]) * -10000.0f;

    // fused qcoef: row = tid>>3, 12 dims per thread, shfl-reduce over 8 lanes
    {
        const int qr = tid >> 3, p = tid & 7;
        const ushort_t* qrow = Qbh + (size_t)(r0 + qr) * DH_;
        float c0 = 0.f, c1 = 0.f, c2 = 0.f;
        #pragma unroll
        for (int j = 0; j < 12; j++) {
            int d = p * 12 + j;
            float e = bf2f(qrow[d]);
            c0 += e * Wd[d];
            c1 += e * Wa[d];
            c2 += e * (bd[d] + ba[d]);
        }
        #pragma unroll
        for (int o = 1; o < 8; o <<= 1) {
            c0 += __shfl_xor(c0, o);
            c1 += __shfl_xor(c1, o);
            c2 += __shfl_xor(c2, o);
        }
        if (p == 0) { qcS[qr * 3] = c0; qcS[qr * 3 + 1] = c1; qcS[qr * 3 + 2] = c2; }
    }
    // Q fragments
    bf16x8 aq[3];
    {
        const ushort_t* qp = Qbh + (size_t)(r0 + rg * 16 + frn) * DH_ + fko;
        aq[0] = *(const bf16x8*)qp;
        aq[1] = *(const bf16x8*)(qp + 32);
        aq[2] = *(const bf16x8*)(qp + 64);
    }
    __syncthreads();
    float qc0[4], qc1[4], qc2[4];
    #pragma unroll
    for (int r = 0; r < 4; r++) {
        int rl = rg * 16 + frg4 + r;
        qc0[r] = qcS[rl * 3]; qc1[r] = qcS[rl * 3 + 1]; qc2[r] = qcS[rl * 3 + 2];
    }
    const float isq = 0.10206207261596577f;   // 1/sqrt(96)

    // staging geometry
    const int kr0r = tid / 12,         kc0 = (tid - kr0r * 12) * 8;
    const int kr1r = (tid + 256) / 12, kc1 = ((tid + 256) % 12) * 8;  // tid<128 only
    const int drow = tid >> 3, dc4 = (tid & 7) * 4;

    // ---- loop 1: 24 chunks of 32 cols; stage -> sync -> consume (dbuf)
    f32x4 acc[24];
    #pragma unroll
    for (int c = 0; c < 24; ++c) {
        char* bufc = sm + (c & 1) * L1B;
        ushort_t* Ks = (ushort_t*)bufc;
        float* Dd = (float*)(bufc + 6656);
        float* Da = (float*)(bufc + 11264);
        *(uint4*)(Ks + kr0r * KSLD + kc0) =
            *(const uint4*)(Kbh + (size_t)(c * 32 + kr0r) * DH_ + kc0);
        if (tid < 128)
            *(uint4*)(Ks + kr1r * KSLD + kc1) =
                *(const uint4*)(Kbh + (size_t)(c * 32 + kr1r) * DH_ + kc1);
        size_t ds = ((size_t)b * S_ + r0 + drow) * S_ + c * 32 + dc4;
        *(float4*)(Dd + drow * DLD + dc4) = *(const float4*)(distm + ds);
        *(float4*)(Da + drow * DLD + dc4) = *(const float4*)(angm + ds);
        __syncthreads();
        const ushort_t* kp = Ks + (cp * 16 + frn) * KSLD + fko;
        f32x4 ca = (f32x4){0.f, 0.f, 0.f, 0.f};
        ca = __builtin_amdgcn_mfma_f32_16x16x32_bf16(aq[0], *(const bf16x8*)kp, ca, 0, 0, 0);
        ca = __builtin_amdgcn_mfma_f32_16x16x32_bf16(aq[1], *(const bf16x8*)(kp + 32), ca, 0, 0, 0);
        ca = __builtin_amdgcn_mfma_f32_16x16x32_bf16(aq[2], *(const bf16x8*)(kp + 64), ca, 0, 0, 0);
        const int jl = cp * 16 + frn;
        float mb = Ms[c * 32 + jl];
        #pragma unroll
        for (int r = 0; r < 4; ++r) {
            int rl = rg * 16 + frg4 + r;
            acc[c][r] = ca[r] * isq + Dd[rl * DLD + jl] * qc0[r]
                      + Da[rl * DLD + jl] * qc1[r] + qc2[r] + mb;
        }
    }

    // ---- softmax (exact)
    float mx[4] = {-1e30f, -1e30f, -1e30f, -1e30f};
    #pragma unroll
    for (int t = 0; t < 24; t++)
        #pragma unroll
        for (int r = 0; r < 4; r++) mx[r] = fmaxf(mx[r], acc[t][r]);
    #pragma unroll
    for (int o = 1; o < 16; o <<= 1)
        #pragma unroll
        for (int r = 0; r < 4; r++) mx[r] = fmaxf(mx[r], __shfl_xor(mx[r], o));
    if (frn == 0)
        #pragma unroll
        for (int r = 0; r < 4; r++) mstat[cp * 32 + rg * 16 + frg4 + r] = mx[r];
    __syncthreads();
    float mf[4], sum[4] = {0.f, 0.f, 0.f, 0.f};
    #pragma unroll
    for (int r = 0; r < 4; r++) {
        int rl = rg * 16 + frg4 + r;
        mf[r] = fmaxf(mstat[rl], mstat[32 + rl]);
    }
    #pragma unroll
    for (int t = 0; t < 24; t++)
        #pragma unroll
        for (int r = 0; r < 4; r++) {
            float e = __expf(acc[t][r] - mf[r]);
            acc[t][r] = e;
            sum[r] += e;
        }
    #pragma unroll
    for (int o = 1; o < 16; o <<= 1)
        #pragma unroll
        for (int r = 0; r < 4; r++) sum[r] += __shfl_xor(sum[r], o);
    if (frn == 0)
        #pragma unroll
        for (int r = 0; r < 4; r++) lstat[cp * 32 + rg * 16 + frg4 + r] = sum[r];
    __syncthreads();
    float inv[4];
    #pragma unroll
    for (int r = 0; r < 4; r++) {
        int rl = rg * 16 + frg4 + r;
        inv[r] = 1.0f / (lstat[rl] + lstat[32 + rl]);
        if (cp == 0 && frn == 0) linv[rl] = inv[r];
    }
    __syncthreads();

    // ---- loop 2: 24 steps of 32 cols; stage V+Ps -> sync -> probs write + PV
    f32x4 accO[3];
    #pragma unroll
    for (int i = 0; i < 3; i++) accO[i] = (f32x4){0.f, 0.f, 0.f, 0.f};
    const int prow = tid >> 3, pc8 = (tid & 7) * 4;
    float* pout = probs + ((size_t)bh * S_ + r0 + prow) * S_;
    const int vrow = tid >> 2, vcv = (tid & 3) * 8;
    const int vrow2 = (tid + 256) >> 2, vcv2 = ((tid + 256) & 3) * 8;
    const bool hasv2 = (tid < 128);
    #pragma unroll
    for (int s = 0; s < 24; ++s) {
        ushort_t* Vs = (ushort_t*)(sm + (s & 1) * 7680);          // [96][40]
        ushort_t* Ps = (ushort_t*)(sm + 15360 + (s & 1) * 2560);  // [32][40]
        *(uint4*)(Vs + vrow * 40 + vcv) =
            *(const uint4*)(Vbh + (size_t)vrow * S_ + s * 32 + vcv);
        if (hasv2)
            *(uint4*)(Vs + vrow2 * 40 + vcv2) =
                *(const uint4*)(Vbh + (size_t)vrow2 * S_ + s * 32 + vcv2);
        #pragma unroll
        for (int r = 0; r < 4; ++r)
            Ps[(rg * 16 + frg4 + r) * 40 + cp * 16 + frn] = f2bf(acc[s][r]);
        __syncthreads();
        {
            float iv = linv[prow];
            float4 p4;
            p4.x = bf2f(Ps[prow * 40 + pc8 + 0]) * iv;
            p4.y = bf2f(Ps[prow * 40 + pc8 + 1]) * iv;
            p4.z = bf2f(Ps[prow * 40 + pc8 + 2]) * iv;
            p4.w = bf2f(Ps[prow * 40 + pc8 + 3]) * iv;
            *(float4*)(pout + s * 32 + pc8) = p4;
        }
        bf16x8 a = *(const bf16x8*)&Ps[(rg * 16 + frn) * 40 + fko];
        #pragma unroll
        for (int nt = 0; nt < 3; ++nt) {
            bf16x8 v = *(const bf16x8*)&Vs[(cp * 48 + nt * 16 + frn) * 40 + fko];
            accO[nt] = __builtin_amdgcn_mfma_f32_16x16x32_bf16(a, v, accO[nt], 0, 0, 0);
        }
    }
    // ---- ctx epilogue
    #pragma unroll
    for (int nt = 0; nt < 3; ++nt) {
        int col = h * DH_ + cp * 48 + nt * 16 + frn;
        #pragma unroll
        for (int r = 0; r < 4; ++r) {
            int row = r0 + rg * 16 + frg4 + r;
            Ctxb[((size_t)(b * S_ + row)) * D_ + col] = f2bf(accO[nt][r] * inv[r]);
        }
    }
}

// ---------------------------------------------------------------- out GEMM 128x64 + bias + residual
// grid (12, 12). 4 waves: wm=(w&1)*64, wn=(w>>1)*32; 4x2 accs.
__global__ __launch_bounds__(256) void k_out(
        const ushort_t* __restrict__ Ctxb, const ushort_t* __restrict__ Wob,
        const float* __restrict__ bo, const float* __restrict__ hidden,
        float* __restrict__ xbuf) {
    __shared__ __align__(16) ushort_t As[128 * 32];
    __shared__ __align__(16) ushort_t Bs[64 * 32];
    const int tid = threadIdx.x, lane = tid & 63, w = tid >> 6;
    const int frn = lane & 15, fko = (lane >> 4) * 8, frg4 = (lane >> 4) * 4;
    const int wm = (w & 1) * 64, wn = (w >> 1) * 32;
    const int m0 = blockIdx.y * 128, n0 = blockIdx.x * 64;
    const int sr = w * 32 + (lane >> 2), sc = (lane & 3) * 8;
    const int srB = w * 16 + (lane >> 2);
    const ushort_t* Ap = Ctxb + (size_t)(m0 + sr) * D_ + sc;
    const ushort_t* Bp = Wob + (size_t)(n0 + srB) * D_ + sc;
    ushort_t* AsW = As + w * 1024;
    ushort_t* BsW = Bs + w * 512;
    f32x4 acc[4][2];
    #pragma unroll
    for (int i = 0; i < 4; i++)
        #pragma unroll
        for (int j = 0; j < 2; j++) acc[i][j] = (f32x4){0.f, 0.f, 0.f, 0.f};
    for (int kt = 0; kt < D_; kt += 32) {
        if (kt) __syncthreads();
        glds16(Ap + kt, AsW);
        glds16(Ap + 16 * D_ + kt, AsW + 512);
        glds16(Bp + kt, BsW);
        __syncthreads();
        bf16x8 a[4], b[2];
        #pragma unroll
        for (int mi = 0; mi < 4; mi++)
            a[mi] = *(const bf16x8*)&As[(wm + mi * 16 + frn) * 32 + fko];
        #pragma unroll
        for (int ni = 0; ni < 2; ni++)
            b[ni] = *(const bf16x8*)&Bs[(wn + ni * 16 + frn) * 32 + fko];
        #pragma unroll
        for (int mi = 0; mi < 4; mi++)
            #pragma unroll
            for (int ni = 0; ni < 2; ni++)
                acc[mi][ni] = __builtin_amdgcn_mfma_f32_16x16x32_bf16(a[mi], b[ni], acc[mi][ni], 0, 0, 0);
    }
    #pragma unroll
    for (int ni = 0; ni < 2; ni++) {
        int gcol = n0 + wn + ni * 16 + frn;
        float bias = bo[gcol];
        #pragma unroll
        for (int mi = 0; mi < 4; mi++) {
            #pragma unroll
            for (int r = 0; r < 4; r++) {
                int grow = m0 + wm + mi * 16 + frg4 + r;
                xbuf[(size_t)grow * D_ + gcol] =
                    acc[mi][ni][r] + bias + hidden[(size_t)grow * D_ + gcol];
            }
        }
    }
}

// ---------------------------------------------------------------- LayerNorm
__global__ __launch_bounds__(256) void k_ln(
        const float* __restrict__ xbuf, const float* __restrict__ g,
        const float* __restrict__ bb, float* __restrict__ out) {
    const float* x = xbuf + (size_t)blockIdx.x * D_;
    const int t = threadIdx.x;
    float a0 = x[t], a1 = x[t + 256], a2 = x[t + 512];
    float s = a0 + a1 + a2;
    float ss = a0 * a0 + a1 * a1 + a2 * a2;
    __shared__ float r1[4], r2[4];
    #pragma unroll
    for (int o = 32; o > 0; o >>= 1) { s += __shfl_down(s, o); ss += __shfl_down(ss, o); }
    if ((t & 63) == 0) { r1[t >> 6] = s; r2[t >> 6] = ss; }
    __syncthreads();
    float ts = r1[0] + r1[1] + r1[2] + r1[3];
    float tss = r2[0] + r2[1] + r2[2] + r2[3];
    float mu = ts * (1.0f / D_);
    float var = tss * (1.0f / D_) - mu * mu;
    float rstd = rsqrtf(var + 1e-5f);
    float* o = out + (size_t)blockIdx.x * D_;
    o[t]       = (a0 - mu) * rstd * g[t]       + bb[t];
    o[t + 256] = (a1 - mu) * rstd * g[t + 256] + bb[t + 256];
    o[t + 512] = (a2 - mu) * rstd * g[t + 512] + bb[t + 512];
}

// ---------------------------------------------------------------- launch
extern "C" void kernel_launch(void* const* d_in, const int* in_sizes, int n_in,
                              void* d_out, int out_size, void* d_ws, size_t ws_size,
                              hipStream_t stream) {
    const float* X     = (const float*)d_in[0];
    const float* distm = (const float*)d_in[1];
    const float* angm  = (const float*)d_in[2];
    const float* mask  = (const float*)d_in[3];
    const float* Wq    = (const float*)d_in[4];
    const float* bq    = (const float*)d_in[5];
    const float* Wk    = (const float*)d_in[6];
    const float* bk    = (const float*)d_in[7];
    const float* Wv    = (const float*)d_in[8];
    const float* bv    = (const float*)d_in[9];
    const float* Wd    = (const float*)d_in[10];
    const float* bd    = (const float*)d_in[11];
    const float* Wa    = (const float*)d_in[12];
    const float* ba    = (const float*)d_in[13];
    const float* Wo    = (const float*)d_in[14];
    const float* bo    = (const float*)d_in[15];
    const float* ln_g  = (const float*)d_in[16];
    const float* ln_b  = (const float*)d_in[17];

    float* outp  = (float*)d_out;                        // [B,S,D]
    float* probs = (float*)d_out + (size_t)B_ * S_ * D_; // [B,H,S,S]

    char* ws = (char*)d_ws;
    ushort_t* Xb    = (ushort_t*)(ws + 0);          // 2,359,296 B
    ushort_t* Wb    = (ushort_t*)(ws + 2359296);    // 4,718,592 B
    ushort_t* Qb    = (ushort_t*)(ws + 7077888);    // 2,359,296 B
    ushort_t* Kb    = (ushort_t*)(ws + 9437184);    // 2,359,296 B
    ushort_t* Vtb   = (ushort_t*)(ws + 11796480);   // 2,359,296 B
    ushort_t* Ctxb  = (ushort_t*)(ws + 14155776);   // 2,359,296 B
    float*    xbuf  = (float*)   (ws + 16515072);   // 4,718,592 B (end ~21.2 MB)

    k_convert<<<3456, 256, 0, stream>>>(X, Wq, Wk, Wv, Wo, Xb, Wb);
    k_qkv<<<dim3(18, 12), 256, 0, stream>>>(Xb, Wb, bq, bk, bv, Qb, Kb, Vtb);
    k_flash<<<384, 256, 0, stream>>>(Qb, Kb, Vtb, Wd, bd, Wa, ba, distm, angm, mask, probs, Ctxb);
    k_out<<<dim3(12, 12), 256, 0, stream>>>(Ctxb, Wb + (size_t)2304 * 768, bo, X, xbuf);
    k_ln<<<1536, 256, 0, stream>>>(xbuf, ln_g, ln_b, outp);
}